// Round 26
// baseline (326.405 us; speedup 1.0000x reference)
//
#include <hip/hip_runtime.h>
#include <cstdint>
#include <cstddef>

typedef __bf16 bf16_t;
typedef __bf16 bf16x8 __attribute__((ext_vector_type(8)));
typedef __bf16 bf16x4 __attribute__((ext_vector_type(4)));
typedef __bf16 bf16x2 __attribute__((ext_vector_type(2)));
typedef float f32x4 __attribute__((ext_vector_type(4)));
typedef float f32x16 __attribute__((ext_vector_type(16)));

#define T_LEN 2048
#define DMODEL 4096
#define NHEADS 32
#define KVHEADS 8
#define HD 128
#define QD 4096   // NHEADS*HD
#define KD 1024   // KVHEADS*HD
#define QKVD 6144 // QD + 2*KD
#define WIN 1024
#define VS 72     // padded stride for attn Vt/P tiles (144B = 9*16B)
#define WMAX 1152 // max mask-window entries per attn block

// ---------------- positions (argmax of segment row, first occurrence) ----------------
__global__ void pos_kernel(const int* __restrict__ seg, int* __restrict__ positions) {
  __shared__ int svals[256], sidx[256];
  int tid = threadIdx.x;
  int bestv = -2147483647 - 1, besti = 0;
  for (int t = tid; t < T_LEN; t += 256) {
    int v = seg[t];
    if (v > bestv) { bestv = v; besti = t; }
  }
  svals[tid] = bestv; sidx[tid] = besti;
  __syncthreads();
  for (int st = 128; st > 0; st >>= 1) {
    if (tid < st) {
      if (svals[tid+st] > svals[tid] || (svals[tid+st] == svals[tid] && sidx[tid+st] < sidx[tid])) {
        svals[tid] = svals[tid+st]; sidx[tid] = sidx[tid+st];
      }
    }
    __syncthreads();
  }
  int amax = sidx[0];
  for (int t = tid; t < T_LEN; t += 256)
    positions[t] = (seg[t] != 0) ? (t - amax) : (1 << 30);
}

// ---------------- rope sin/cos table ----------------
__global__ void sincos_kernel(const int* __restrict__ positions, float* __restrict__ sc) {
  int t = blockIdx.x, i = threadIdx.x; // 64 threads
  float inv = expf(-(float)i * (logf(500000.0f) / 64.0f));
  float ang = (float)positions[t] * inv;
  sc[(t*64 + i)*2 + 0] = sinf(ang);
  sc[(t*64 + i)*2 + 1] = cosf(ang);
}

// ---------------- f32 -> bf16 convert (8/thread) ----------------
__global__ void cvt_kernel(const float* __restrict__ in, bf16_t* __restrict__ out, int n) {
  int i = (blockIdx.x * blockDim.x + threadIdx.x) * 8;
  if (i >= n) return;
  float4 a = *(const float4*)(in + i);
  float4 b = *(const float4*)(in + i + 4);
  bf16x8 o;
  o[0]=(bf16_t)a.x; o[1]=(bf16_t)a.y; o[2]=(bf16_t)a.z; o[3]=(bf16_t)a.w;
  o[4]=(bf16_t)b.x; o[5]=(bf16_t)b.y; o[6]=(bf16_t)b.z; o[7]=(bf16_t)b.w;
  *(bf16x8*)(out + i) = o;
}

// ---------------- transpose + convert: W[K][N] f32 -> Wt[N][K] bf16 ----------------
__global__ void transcvt_kernel(const float* __restrict__ W, bf16_t* __restrict__ Wt, int K, int N) {
  __shared__ float tile[32][33];
  int tx = threadIdx.x, ty = threadIdx.y; // 32 x 8
  int bx = blockIdx.x, by = blockIdx.y;
  #pragma unroll
  for (int i = 0; i < 4; i++) {
    int k = by*32 + ty + i*8;
    tile[ty + i*8][tx] = W[(size_t)k * N + bx*32 + tx];
  }
  __syncthreads();
  int t = ty*32 + tx;
  int n = t >> 3;
  int kq = t & 7;
  bf16x4 v;
  #pragma unroll
  for (int e = 0; e < 4; e++) v[e] = (bf16_t)tile[kq*4 + e][n];
  *(bf16x4*)(Wt + (size_t)(bx*32 + n) * K + by*32 + kq*4) = v;
}

__device__ __forceinline__ void gld_lds16(const void* g, void* l) {
  __builtin_amdgcn_global_load_lds((__attribute__((address_space(1))) void*)g,
                                   (__attribute__((address_space(3))) void*)l, 16, 0, 0);
}

// ---------------- GEMM1: 128x192, 4 waves x (64x96), 32x32x16 MFMA, 1-barrier/K-step ----------------
// R25 diagnosis: wall ~ LDS-pipe + MFMA-pipe (serialized per-wave, dep-limited,
// 2 waves/SIMD can't hide). Lever: 32x32x16 MFMA = -13% MFMA pipe cycles
// (m119: 8.07 vs 4.85cy/instr at equal FLOP) and HALF the instruction count
// (24 vs 48/wave-step) with identical LDS traffic and register budget.
// Operand layout (analog of working 16x16 pattern): lane(l&31)=row/col,
// k=(l>>5)*8+e -> chunk = ks*2+(l>>5), same XOR swizzle. C/D layout
// (guide-verified m74/m101): col=lane&31, row=(reg&3)+8*(reg>>2)+4*(lane>>5).
__global__ __launch_bounds__(256, 2) void gemm1_kernel(
    const bf16_t* __restrict__ A, const bf16_t* __restrict__ Bt,
    bf16_t* __restrict__ Cb, int M, int N, int K, int NBM) {
  __shared__ bf16_t As[2 * 128 * 64];   // 32 KB
  __shared__ bf16_t Bs[2 * 192 * 64];   // 48 KB
  int tid = threadIdx.x;
  int w = tid >> 6, l = tid & 63;
  int l32 = l & 31, lh = l >> 5;
  int wr = w >> 1, wc = w & 1;          // 2M x 2N waves; wave = 64 x 96
  int nwg = gridDim.x;
  int wg  = blockIdx.x;
  int cpx = nwg >> 3;
  int swz = (wg & 7) * cpx + (wg >> 3);
  int bm = swz % NBM, bn = swz / NBM;
  const int NT = K >> 6;

  auto stageA = [&](int tt, int h) {
    bf16_t* ldsb = As + (tt & 1)*8192 + h*4096;
    #pragma unroll
    for (int i = 0; i < 2; i++) {
      int c = tid + i*256;
      int row = c >> 3;
      int scn = (c & 7) ^ (row & 7);
      gld_lds16(A + ((size_t)bm*128 + h*64 + row) * K + tt*64 + scn*8,
                ldsb + i*2048 + w*512);
    }
  };
  auto stageB = [&](int tt, int u) {
    bf16_t* ldsb = Bs + (tt & 1)*12288 + u*4096;
    #pragma unroll
    for (int i = 0; i < 2; i++) {
      int c = tid + i*256;
      int row = c >> 3;
      int scn = (c & 7) ^ (row & 7);
      gld_lds16(Bt + ((size_t)bn*192 + u*64 + row) * K + tt*64 + scn*8,
                ldsb + i*2048 + w*512);
    }
  };
  // 32x32x16 operand frags: row/col = base + (l&31); k = (l>>5)*8 + e of the
  // 16-wide k-slice ks -> 16B chunk index ks*2 + lh, XOR-swizzled by row.
  auto afrag32 = [&](int b2, int rt, int ks) -> bf16x8 {
    int row = wr*64 + rt*32 + l32;
    int chunk = (ks*2 + lh) ^ (row & 7);
    return *(const bf16x8*)((const char*)(As + b2*8192) + row*128 + chunk*16);
  };
  auto bfrag32 = [&](int b2, int ct, int ks) -> bf16x8 {
    int row = wc*96 + ct*32 + l32;
    int chunk = (ks*2 + lh) ^ (row & 7);
    return *(const bf16x8*)((const char*)(Bs + b2*12288) + row*128 + chunk*16);
  };

  f32x16 acc[2][3] = {};
  bf16x8 a[2][4], bbf[3][4];

  // prologue: stage tile0 fully, drain
  stageA(0, 0); stageA(0, 1); stageB(0, 0); stageB(0, 1); stageB(0, 2);
  asm volatile("s_waitcnt vmcnt(0)" ::: "memory");
  __builtin_amdgcn_s_barrier();

  for (int t = 0; t < NT; t++) {
    int b = t & 1;
    // read burst (20 b128 of buffer b)
    #pragma unroll
    for (int rt = 0; rt < 2; rt++)
      #pragma unroll
      for (int ks = 0; ks < 4; ks++)
        a[rt][ks] = afrag32(b, rt, ks);
    #pragma unroll
    for (int ct = 0; ct < 3; ct++)
      #pragma unroll
      for (int ks = 0; ks < 4; ks++)
        bbf[ct][ks] = bfrag32(b, ct, ks);
    // stage tile t+1 -> b^1
    if (t + 1 < NT) {
      stageA(t + 1, 0); stageA(t + 1, 1);
      stageB(t + 1, 0); stageB(t + 1, 1); stageB(t + 1, 2);
    }
    __builtin_amdgcn_s_setprio(1);
    #pragma unroll
    for (int rt = 0; rt < 2; rt++)
      #pragma unroll
      for (int ct = 0; ct < 3; ct++)
        #pragma unroll
        for (int ks = 0; ks < 4; ks++)
          acc[rt][ct] = __builtin_amdgcn_mfma_f32_32x32x16_bf16(a[rt][ks], bbf[ct][ks], acc[rt][ct], 0, 0, 0);
    __builtin_amdgcn_s_setprio(0);
    asm volatile("s_waitcnt vmcnt(0)" ::: "memory");
    __builtin_amdgcn_s_barrier();
  }

  #pragma unroll
  for (int rt = 0; rt < 2; rt++) {
    #pragma unroll
    for (int ct = 0; ct < 3; ct++) {
      #pragma unroll
      for (int reg = 0; reg < 16; reg++) {
        int row = bm*128 + wr*64 + rt*32 + (reg & 3) + 8*(reg >> 2) + 4*lh;
        int col = bn*192 + wc*96 + ct*32 + l32;
        Cb[(size_t)row * N + col] = (bf16_t)acc[rt][ct][reg];
      }
    }
  }
}

// ---------------- GEMM2: 128x256, 8 waves x (64x64), 1-barrier/K-step, f32 out ----------------
__global__ __launch_bounds__(512, 2) void gemm2_kernel(
    const bf16_t* __restrict__ A, const bf16_t* __restrict__ Bt,
    float* __restrict__ Cf, int M, int N, int K, int NBM) {
  __shared__ bf16_t As[2 * 128 * 64];   // 32 KB
  __shared__ bf16_t Bs[2 * 256 * 64];   // 64 KB
  int tid = threadIdx.x;
  int w = tid >> 6, l = tid & 63, lr = l & 15, lg = l >> 4;
  int wr = w >> 2, wc = w & 3;          // 2M x 4N waves; wave = 64 x 64
  int nwg = gridDim.x;
  int wg  = blockIdx.x;
  int cpx = nwg >> 3;
  int swz = (wg & 7) * cpx + (wg >> 3);
  int bm = swz % NBM, bn = swz / NBM;
  const int NT = K >> 6;

  auto stageA = [&](int tt) {
    bf16_t* ldsb = As + (tt & 1)*8192;
    #pragma unroll
    for (int i = 0; i < 2; i++) {
      int c = tid + i*512;
      int row = c >> 3;
      int scn = (c & 7) ^ (row & 7);
      gld_lds16(A + ((size_t)bm*128 + row) * K + tt*64 + scn*8,
                ldsb + i*4096 + w*512);
    }
  };
  auto stageB = [&](int tt, int u) {
    bf16_t* ldsb = Bs + (tt & 1)*16384 + u*8192;
    #pragma unroll
    for (int i = 0; i < 2; i++) {
      int c = tid + i*512;
      int row = c >> 3;
      int scn = (c & 7) ^ (row & 7);
      gld_lds16(Bt + ((size_t)bn*256 + u*128 + row) * K + tt*64 + scn*8,
                ldsb + i*4096 + w*512);
    }
  };
  auto afrag = [&](int b2, int row, int kk) -> bf16x8 {
    int chunk = (kk*4 + lg) ^ (row & 7);
    return *(const bf16x8*)((const char*)(As + b2*8192) + row*128 + chunk*16);
  };
  auto bfrag = [&](int b2, int row, int kk) -> bf16x8 {
    int chunk = (kk*4 + lg) ^ (row & 7);
    return *(const bf16x8*)((const char*)(Bs + b2*16384) + row*128 + chunk*16);
  };

  f32x4 acc[4][4] = {};
  bf16x8 a[4][2], bb[4][2];

  stageA(0); stageB(0, 0); stageB(0, 1);
  asm volatile("s_waitcnt vmcnt(0)" ::: "memory");
  __builtin_amdgcn_s_barrier();

  for (int t = 0; t < NT; t++) {
    int b = t & 1;
    #pragma unroll
    for (int fm = 0; fm < 4; fm++)
      #pragma unroll
      for (int kk = 0; kk < 2; kk++)
        a[fm][kk] = afrag(b, wr*64 + fm*16 + lr, kk);
    #pragma unroll
    for (int fn = 0; fn < 4; fn++)
      #pragma unroll
      for (int kk = 0; kk < 2; kk++)
        bb[fn][kk] = bfrag(b, wc*64 + fn*16 + lr, kk);
    if (t + 1 < NT) { stageA(t + 1); stageB(t + 1, 0); stageB(t + 1, 1); }
    __builtin_amdgcn_s_setprio(1);
    #pragma unroll
    for (int fm = 0; fm < 4; fm++)
      #pragma unroll
      for (int fn = 0; fn < 4; fn++)
        #pragma unroll
        for (int kk = 0; kk < 2; kk++)
          acc[fm][fn] = __builtin_amdgcn_mfma_f32_16x16x32_bf16(a[fm][kk], bb[fn][kk], acc[fm][fn], 0, 0, 0);
    __builtin_amdgcn_s_setprio(0);
    asm volatile("s_waitcnt vmcnt(0)" ::: "memory");
    __builtin_amdgcn_s_barrier();
  }

  #pragma unroll
  for (int fm = 0; fm < 4; fm++) {
    #pragma unroll
    for (int fn = 0; fn < 4; fn++) {
      #pragma unroll
      for (int r2 = 0; r2 < 4; r2++) {
        int row = bm*128 + wr*64 + fm*16 + lg*4 + r2;
        int col = bn*256 + wc*64 + fn*16 + lr;
        Cf[(size_t)row * N + col] = acc[fm][fn][r2];
      }
    }
  }
}

// ---------------- fused RMSNorm + RoPE + q-scale ----------------
__global__ __launch_bounds__(256) void normrope_kernel(bf16_t* __restrict__ qkv,
    const float* __restrict__ qw, const float* __restrict__ kw,
    const float* __restrict__ sc) {
  int t = blockIdx.x;
  int tid = threadIdx.x;
  bf16_t* qrow = qkv + (size_t)t * QKVD;
  bf16_t* krow = qrow + QD;
  __shared__ float red[8];
  float s = 0.f;
  {
    const bf16x8* p = (const bf16x8*)(qrow + tid*16);
    bf16x8 v0 = p[0], v1 = p[1];
    #pragma unroll
    for (int j = 0; j < 8; j++) { float a = (float)v0[j], b = (float)v1[j]; s += a*a + b*b; }
  }
  #pragma unroll
  for (int o = 32; o; o >>= 1) s += __shfl_xor(s, o);
  if ((tid & 63) == 0) red[tid >> 6] = s;
  float sk = 0.f;
  {
    bf16x4 v = *(const bf16x4*)(krow + tid*4);
    #pragma unroll
    for (int j = 0; j < 4; j++) { float a = (float)v[j]; sk += a*a; }
  }
  #pragma unroll
  for (int o = 32; o; o >>= 1) sk += __shfl_xor(sk, o);
  if ((tid & 63) == 0) red[4 + (tid >> 6)] = sk;
  __syncthreads();
  float rq = rsqrtf((red[0]+red[1]+red[2]+red[3]) / (float)QD + 1e-6f);
  float rk = rsqrtf((red[4]+red[5]+red[6]+red[7]) / (float)KD + 1e-6f);
  const float ascale = 0.08838834764831845f;
  for (int p = tid; p < 2048; p += 256) {
    int hh = p >> 6, i = p & 63;
    int i1 = hh*HD + i, i2 = i1 + 64;
    float x1 = (float)qrow[i1] * rq * qw[i1];
    float x2 = (float)qrow[i2] * rq * qw[i2];
    float sn = sc[(t*64 + i)*2 + 0], cs = sc[(t*64 + i)*2 + 1];
    qrow[i1] = (bf16_t)((x1*cs - x2*sn) * ascale);
    qrow[i2] = (bf16_t)((x2*cs + x1*sn) * ascale);
  }
  for (int p = tid; p < 512; p += 256) {
    int hh = p >> 6, i = p & 63;
    int i1 = hh*HD + i, i2 = i1 + 64;
    float x1 = (float)krow[i1] * rk * kw[i1];
    float x2 = (float)krow[i2] * rk * kw[i2];
    float sn = sc[(t*64 + i)*2 + 0], cs = sc[(t*64 + i)*2 + 1];
    krow[i1] = (bf16_t)(x1*cs - x2*sn);
    krow[i2] = (bf16_t)(x2*cs + x1*sn);
  }
}

// ---------------- flash attention: 4 waves x 32 q-rows (R19-proven, unchanged) ----------------
__global__ __launch_bounds__(256, 2) void attn_kernel(const bf16_t* __restrict__ qkv,
    const int* __restrict__ positions, const int* __restrict__ seg,
    bf16_t* __restrict__ O) {
  __shared__ bf16_t Ks[2][64 * HD];   // 32 KB double-buffered
  __shared__ bf16_t Vt[HD * VS];      // 18 KB
  __shared__ bf16_t P[4][32 * VS];    // 18.4 KB
  __shared__ int posL[WMAX];
  __shared__ int segL[WMAX];
  int tid = threadIdx.x;
  int w = tid >> 6, l = tid & 63, lr = l & 15, lg = l >> 4;
  int qb = (gridDim.x - 1 - blockIdx.x) * 128;   // long blocks first
  int h = blockIdx.y;
  int kvh = h >> 2;
  int q0 = qb + w * 32;
  const bf16_t* Kg = qkv + QD + (size_t)kvh * HD;
  const bf16_t* Vg = qkv + QD + KD + (size_t)kvh * HD;

  bf16x8 qf[2][4];
  #pragma unroll
  for (int g = 0; g < 2; g++) {
    const bf16_t* Qrow = qkv + (size_t)(q0 + g*16 + lr) * QKVD + h * HD;
    #pragma unroll
    for (int c = 0; c < 4; c++) qf[g][c] = *(const bf16x8*)(Qrow + c*32 + lg*8);
  }
  int pos_i[2][4], seg_i[2][4];
  #pragma unroll
  for (int g = 0; g < 2; g++)
    #pragma unroll
    for (int r = 0; r < 4; r++) {
      int i = q0 + g*16 + lg*4 + r;
      pos_i[g][r] = positions[i]; seg_i[g][r] = seg[i];
    }
  f32x4 o[2][8] = {};
  float m[2][4], lsum[2][4];
  #pragma unroll
  for (int g = 0; g < 2; g++)
    #pragma unroll
    for (int r = 0; r < 4; r++) { m[g][r] = -__builtin_inff(); lsum[g][r] = 0.f; }

  int vkp[2], vdg[2];
  #pragma unroll
  for (int si = 0; si < 2; si++) { int item = tid + si*256; vkp[si] = item & 31; vdg[si] = item >> 5; }
  bf16x8 vrA[2], vrB[2];

  auto issueK = [&](int j0, int buf) {
    #pragma unroll
    for (int i = 0; i < 4; i++) {
      int c = tid + i*256;
      int row = c >> 4;
      int scn = (c & 15) ^ (row & 7);
      gld_lds16(Kg + (size_t)(j0 + row) * QKVD + scn*8,
                (char*)Ks[buf] + (size_t)(i*256 + (tid & 192))*16);
    }
  };
  auto loadV = [&](int j0) {
    #pragma unroll
    for (int si = 0; si < 2; si++) {
      const bf16_t* vp = Vg + (size_t)(j0 + 2*vkp[si]) * QKVD + vdg[si]*8;
      vrA[si] = *(const bf16x8*)vp;
      vrB[si] = *(const bf16x8*)(vp + QKVD);
    }
  };

  int jstart = qb - (WIN - 1); if (jstart < 0) jstart = 0; jstart &= ~63;
  const int jlast = qb + 64;
  const int wlen = qb + 128 - jstart;
  loadV(jstart);
  issueK(jstart, 0);
  for (int i = tid; i < wlen; i += 256) {
    posL[i] = positions[jstart + i];
    segL[i] = seg[jstart + i];
  }
  asm volatile("s_waitcnt lgkmcnt(0)" ::: "memory");
  __builtin_amdgcn_s_barrier();

  int nt = 0;
  for (int j0 = jstart; j0 <= jlast; j0 += 64, nt++) {
    int b = nt & 1;
    bool hasNext = (j0 + 64 <= jlast);
    #pragma unroll
    for (int si = 0; si < 2; si++) {
      #pragma unroll
      for (int e = 0; e < 8; e++) {
        bf16x2 pr; pr[0] = vrA[si][e]; pr[1] = vrB[si][e];
        *(bf16x2*)(Vt + (vdg[si]*8 + e)*VS + 2*vkp[si]) = pr;
      }
    }
    int pj[4], sj[4];
    #pragma unroll
    for (int kt = 0; kt < 4; kt++) {
      int ji = j0 - jstart + kt*16 + lr;
      pj[kt] = posL[ji]; sj[kt] = segL[ji];
    }
    asm volatile("" ::: "memory");
    if (hasNext) { loadV(j0 + 64); issueK(j0 + 64, b ^ 1); }
    asm volatile("" ::: "memory");
    if (hasNext) asm volatile("s_waitcnt vmcnt(8) lgkmcnt(0)" ::: "memory");
    else         asm volatile("s_waitcnt vmcnt(0) lgkmcnt(0)" ::: "memory");
    __builtin_amdgcn_s_barrier();

    bool active = (j0 <= q0 + 31) && (j0 + 63 >= q0 - (WIN - 1));
    if (active) {
      f32x4 s[2][4] = {};
      __builtin_amdgcn_s_setprio(1);
      #pragma unroll
      for (int kt = 0; kt < 4; kt++) {
        int row = kt*16 + lr;
        const char* kb = (const char*)Ks[b] + row*256;
        #pragma unroll
        for (int c = 0; c < 4; c++) {
          bf16x8 kf = *(const bf16x8*)(kb + (((c*4 + lg) ^ (row & 7)) * 16));
          #pragma unroll
          for (int g = 0; g < 2; g++)
            s[g][kt] = __builtin_amdgcn_mfma_f32_16x16x32_bf16(qf[g][c], kf, s[g][kt], 0, 0, 0);
        }
      }
      __builtin_amdgcn_s_setprio(0);
      #pragma unroll
      for (int kt = 0; kt < 4; kt++)
        #pragma unroll
        for (int g = 0; g < 2; g++)
          #pragma unroll
          for (int r = 0; r < 4; r++) {
            bool valid = (pj[kt] <= pos_i[g][r]) && (pos_i[g][r] - pj[kt] < WIN) && (seg_i[g][r] == sj[kt]) && (sj[kt] != 0);
            s[g][kt][r] = valid ? s[g][kt][r] : -__builtin_inff();
          }
      #pragma unroll
      for (int g = 0; g < 2; g++)
        #pragma unroll
        for (int r = 0; r < 4; r++) {
          float smax = fmaxf(fmaxf(s[g][0][r], s[g][1][r]), fmaxf(s[g][2][r], s[g][3][r]));
          if (__any(smax > m[g][r] + 8.f)) {
            float rm = smax;
            #pragma unroll
            for (int o2 = 1; o2 < 16; o2 <<= 1) rm = fmaxf(rm, __shfl_xor(rm, o2));
            if (rm > m[g][r] + 8.f) {
              float rescale = __expf(m[g][r] - rm);
              lsum[g][r] *= rescale;
              #pragma unroll
              for (int n = 0; n < 8; n++) o[g][n][r] *= rescale;
              m[g][r] = rm;
            }
          }
          float mub = fmaxf(m[g][r], -1e37f);
          float p0 = __expf(s[g][0][r] - mub);
          float p1 = __expf(s[g][1][r] - mub);
          float p2 = __expf(s[g][2][r] - mub);
          float p3 = __expf(s[g][3][r] - mub);
          lsum[g][r] += (p0 + p1) + (p2 + p3);
          int prow = (g*16 + lg*4 + r) * VS;
          P[w][prow + lr]      = (bf16_t)p0;
          P[w][prow + 16 + lr] = (bf16_t)p1;
          P[w][prow + 32 + lr] = (bf16_t)p2;
          P[w][prow + 48 + lr] = (bf16_t)p3;
        }
      __builtin_amdgcn_s_setprio(1);
      #pragma unroll
      for (int ks = 0; ks < 2; ks++) {
        bf16x8 pa[2];
        #pragma unroll
        for (int g = 0; g < 2; g++)
          pa[g] = *(const bf16x8*)(&P[w][(g*16 + lr)*VS + ks*32 + lg*8]);
        #pragma unroll
        for (int n = 0; n < 8; n++) {
          bf16x8 vb = *(const bf16x8*)(&Vt[(n*16 + lr)*VS + ks*32 + lg*8]);
          #pragma unroll
          for (int g = 0; g < 2; g++)
            o[g][n] = __builtin_amdgcn_mfma_f32_16x16x32_bf16(pa[g], vb, o[g][n], 0, 0, 0);
        }
      }
      __builtin_amdgcn_s_setprio(0);
    }
    __builtin_amdgcn_s_barrier();
  }
  #pragma unroll
  for (int g = 0; g < 2; g++)
    #pragma unroll
    for (int r = 0; r < 4; r++) {
      float ls = lsum[g][r];
      #pragma unroll
      for (int o2 = 1; o2 < 16; o2 <<= 1) ls += __shfl_xor(ls, o2);
      float inv = ls > 0.f ? 1.f / ls : 0.f;
      int row = q0 + g*16 + lg*4 + r;
      #pragma unroll
      for (int n = 0; n < 8; n++)
        O[(size_t)row * QD + h*HD + n*16 + lr] = (bf16_t)(o[g][n][r] * inv);
    }
}

// ---------------- launch ----------------
extern "C" void kernel_launch(void* const* d_in, const int* in_sizes, int n_in,
                              void* d_out, int out_size, void* d_ws, size_t ws_size,
                              hipStream_t stream) {
  (void)in_sizes; (void)n_in; (void)out_size; (void)ws_size;
  const float* x  = (const float*)d_in[0];
  const float* Wq = (const float*)d_in[1];
  const float* Wk = (const float*)d_in[2];
  const float* Wv = (const float*)d_in[3];
  const float* Wo = (const float*)d_in[4];
  const float* qw = (const float*)d_in[5];
  const float* kw = (const float*)d_in[6];
  const int*  seg = (const int*)d_in[7];
  float* out = (float*)d_out;

  char* base = (char*)d_ws;
  size_t off = 0;
  auto alloc = [&](size_t b) { void* r = base + off; off = (off + b + 255) & ~(size_t)255; return r; };
  bf16_t* xb    = (bf16_t*)alloc((size_t)T_LEN * DMODEL * 2);
  bf16_t* Wallt = (bf16_t*)alloc((size_t)QKVD * DMODEL * 2);
  bf16_t* Wot   = (bf16_t*)alloc((size_t)DMODEL * QD * 2);
  bf16_t* qkv   = (bf16_t*)alloc((size_t)T_LEN * QKVD * 2);
  int*    posi  = (int*)alloc((size_t)T_LEN * 4);
  float*  sc    = (float*)alloc((size_t)T_LEN * 64 * 2 * 4);
  bf16_t* ao    = xb;  // attention output aliases xb (xb dead after GEMM1)

  pos_kernel<<<1, 256, 0, stream>>>(seg, posi);
  sincos_kernel<<<T_LEN, 64, 0, stream>>>(posi, sc);
  cvt_kernel<<<(T_LEN * DMODEL / 8 + 255) / 256, 256, 0, stream>>>(x, xb, T_LEN * DMODEL);
  transcvt_kernel<<<dim3(QD/32, DMODEL/32), dim3(32, 8), 0, stream>>>(Wq, Wallt, DMODEL, QD);
  transcvt_kernel<<<dim3(KD/32, DMODEL/32), dim3(32, 8), 0, stream>>>(Wk, Wallt + (size_t)QD * DMODEL, DMODEL, KD);
  transcvt_kernel<<<dim3(KD/32, DMODEL/32), dim3(32, 8), 0, stream>>>(Wv, Wallt + (size_t)(QD + KD) * DMODEL, DMODEL, KD);
  transcvt_kernel<<<dim3(DMODEL/32, QD/32), dim3(32, 8), 0, stream>>>(Wo, Wot, QD, DMODEL);
  gemm1_kernel<<<dim3((T_LEN/128)*(QKVD/192)), 256, 0, stream>>>(
      xb, Wallt, qkv, T_LEN, QKVD, DMODEL, T_LEN/128);
  normrope_kernel<<<T_LEN, 256, 0, stream>>>(qkv, qw, kw, sc);
  attn_kernel<<<dim3(T_LEN/128, NHEADS), 256, 0, stream>>>(qkv, posi, seg, ao);
  gemm2_kernel<<<dim3((T_LEN/128)*(DMODEL/256)), 512, 0, stream>>>(
      ao, Wot, out, T_LEN, DMODEL, QD, T_LEN/128);
}

// Round 27
// 314.200 us; speedup vs baseline: 1.0388x; 1.0388x over previous
//
#include <hip/hip_runtime.h>
#include <cstdint>
#include <cstddef>

typedef __bf16 bf16_t;
typedef __bf16 bf16x8 __attribute__((ext_vector_type(8)));
typedef __bf16 bf16x4 __attribute__((ext_vector_type(4)));
typedef __bf16 bf16x2 __attribute__((ext_vector_type(2)));
typedef float f32x4 __attribute__((ext_vector_type(4)));

#define T_LEN 2048
#define DMODEL 4096
#define NHEADS 32
#define KVHEADS 8
#define HD 128
#define QD 4096   // NHEADS*HD
#define KD 1024   // KVHEADS*HD
#define QKVD 6144 // QD + 2*KD
#define WIN 1024
#define VS 72     // padded stride for attn Vt/P tiles (144B = 9*16B)
#define WMAX 1152 // max mask-window entries per attn block

// ---------------- positions (argmax of segment row, first occurrence) ----------------
__global__ void pos_kernel(const int* __restrict__ seg, int* __restrict__ positions) {
  __shared__ int svals[256], sidx[256];
  int tid = threadIdx.x;
  int bestv = -2147483647 - 1, besti = 0;
  for (int t = tid; t < T_LEN; t += 256) {
    int v = seg[t];
    if (v > bestv) { bestv = v; besti = t; }
  }
  svals[tid] = bestv; sidx[tid] = besti;
  __syncthreads();
  for (int st = 128; st > 0; st >>= 1) {
    if (tid < st) {
      if (svals[tid+st] > svals[tid] || (svals[tid+st] == svals[tid] && sidx[tid+st] < sidx[tid])) {
        svals[tid] = svals[tid+st]; sidx[tid] = sidx[tid+st];
      }
    }
    __syncthreads();
  }
  int amax = sidx[0];
  for (int t = tid; t < T_LEN; t += 256)
    positions[t] = (seg[t] != 0) ? (t - amax) : (1 << 30);
}

// ---------------- rope sin/cos table ----------------
__global__ void sincos_kernel(const int* __restrict__ positions, float* __restrict__ sc) {
  int t = blockIdx.x, i = threadIdx.x; // 64 threads
  float inv = expf(-(float)i * (logf(500000.0f) / 64.0f));
  float ang = (float)positions[t] * inv;
  sc[(t*64 + i)*2 + 0] = sinf(ang);
  sc[(t*64 + i)*2 + 1] = cosf(ang);
}

// ---------------- f32 -> bf16 convert (8/thread) ----------------
__global__ void cvt_kernel(const float* __restrict__ in, bf16_t* __restrict__ out, int n) {
  int i = (blockIdx.x * blockDim.x + threadIdx.x) * 8;
  if (i >= n) return;
  float4 a = *(const float4*)(in + i);
  float4 b = *(const float4*)(in + i + 4);
  bf16x8 o;
  o[0]=(bf16_t)a.x; o[1]=(bf16_t)a.y; o[2]=(bf16_t)a.z; o[3]=(bf16_t)a.w;
  o[4]=(bf16_t)b.x; o[5]=(bf16_t)b.y; o[6]=(bf16_t)b.z; o[7]=(bf16_t)b.w;
  *(bf16x8*)(out + i) = o;
}

// ---------------- transpose + convert: W[K][N] f32 -> Wt[N][K] bf16 ----------------
__global__ void transcvt_kernel(const float* __restrict__ W, bf16_t* __restrict__ Wt, int K, int N) {
  __shared__ float tile[32][33];
  int tx = threadIdx.x, ty = threadIdx.y; // 32 x 8
  int bx = blockIdx.x, by = blockIdx.y;
  #pragma unroll
  for (int i = 0; i < 4; i++) {
    int k = by*32 + ty + i*8;
    tile[ty + i*8][tx] = W[(size_t)k * N + bx*32 + tx];
  }
  __syncthreads();
  int t = ty*32 + tx;
  int n = t >> 3;
  int kq = t & 7;
  bf16x4 v;
  #pragma unroll
  for (int e = 0; e < 4; e++) v[e] = (bf16_t)tile[kq*4 + e][n];
  *(bf16x4*)(Wt + (size_t)(bx*32 + n) * K + by*32 + kq*4) = v;
}

__device__ __forceinline__ void gld_lds16(const void* g, void* l) {
  __builtin_amdgcn_global_load_lds((__attribute__((address_space(1))) void*)g,
                                   (__attribute__((address_space(3))) void*)l, 16, 0, 0);
}

// ---------------- GEMM1: 128x192, 4 waves x (64x96), 1-barrier/K-step (R24-proven) ----------------
// R26 lesson: 32x32x16 frags on this LDS layout = 4-way bank conflict (32 rows
// x 8 slots, rows all bank-0-aligned) -> reverted to the conflict-free 16x16.
__global__ __launch_bounds__(256, 2) void gemm1_kernel(
    const bf16_t* __restrict__ A, const bf16_t* __restrict__ Bt,
    bf16_t* __restrict__ Cb, int M, int N, int K, int NBM) {
  __shared__ bf16_t As[2 * 128 * 64];   // 32 KB
  __shared__ bf16_t Bs[2 * 192 * 64];   // 48 KB
  int tid = threadIdx.x;
  int w = tid >> 6, l = tid & 63, lr = l & 15, lg = l >> 4;
  int wr = w >> 1, wc = w & 1;          // 2M x 2N waves; wave = 64 x 96
  int nwg = gridDim.x;
  int wg  = blockIdx.x;
  int cpx = nwg >> 3;
  int swz = (wg & 7) * cpx + (wg >> 3);
  int bm = swz % NBM, bn = swz / NBM;
  const int NT = K >> 6;

  auto stageA = [&](int tt, int h) {
    bf16_t* ldsb = As + (tt & 1)*8192 + h*4096;
    #pragma unroll
    for (int i = 0; i < 2; i++) {
      int c = tid + i*256;
      int row = c >> 3;
      int scn = (c & 7) ^ (row & 7);
      gld_lds16(A + ((size_t)bm*128 + h*64 + row) * K + tt*64 + scn*8,
                ldsb + i*2048 + w*512);
    }
  };
  auto stageB = [&](int tt, int u) {
    bf16_t* ldsb = Bs + (tt & 1)*12288 + u*4096;
    #pragma unroll
    for (int i = 0; i < 2; i++) {
      int c = tid + i*256;
      int row = c >> 3;
      int scn = (c & 7) ^ (row & 7);
      gld_lds16(Bt + ((size_t)bn*192 + u*64 + row) * K + tt*64 + scn*8,
                ldsb + i*2048 + w*512);
    }
  };
  auto afrag = [&](int b2, int row, int kk) -> bf16x8 {
    int chunk = (kk*4 + lg) ^ (row & 7);
    return *(const bf16x8*)((const char*)(As + b2*8192) + row*128 + chunk*16);
  };
  auto bfrag = [&](int b2, int row, int kk) -> bf16x8 {
    int chunk = (kk*4 + lg) ^ (row & 7);
    return *(const bf16x8*)((const char*)(Bs + b2*12288) + row*128 + chunk*16);
  };

  f32x4 acc[4][6] = {};
  bf16x8 a[4][2], bb[6][2];

  // prologue: stage tile0 fully, drain
  stageA(0, 0); stageA(0, 1); stageB(0, 0); stageB(0, 1); stageB(0, 2);
  asm volatile("s_waitcnt vmcnt(0)" ::: "memory");
  __builtin_amdgcn_s_barrier();

  for (int t = 0; t < NT; t++) {
    int b = t & 1;
    // read burst (20 ds_reads of buffer b)
    #pragma unroll
    for (int fm = 0; fm < 4; fm++)
      #pragma unroll
      for (int kk = 0; kk < 2; kk++)
        a[fm][kk] = afrag(b, wr*64 + fm*16 + lr, kk);
    #pragma unroll
    for (int fn = 0; fn < 6; fn++)
      #pragma unroll
      for (int kk = 0; kk < 2; kk++)
        bb[fn][kk] = bfrag(b, wc*96 + fn*16 + lr, kk);
    // stage tile t+1 -> b^1 (last readers finished before end-of-(t-1) barrier)
    if (t + 1 < NT) {
      stageA(t + 1, 0); stageA(t + 1, 1);
      stageB(t + 1, 0); stageB(t + 1, 1); stageB(t + 1, 2);
    }
    asm volatile("s_waitcnt lgkmcnt(0)" ::: "memory");
    __builtin_amdgcn_s_setprio(1);
    #pragma unroll
    for (int fm = 0; fm < 4; fm++)
      #pragma unroll
      for (int fn = 0; fn < 6; fn++)
        #pragma unroll
        for (int kk = 0; kk < 2; kk++)
          acc[fm][fn] = __builtin_amdgcn_mfma_f32_16x16x32_bf16(a[fm][kk], bb[fn][kk], acc[fm][fn], 0, 0, 0);
    __builtin_amdgcn_s_setprio(0);
    asm volatile("s_waitcnt vmcnt(0)" ::: "memory");
    __builtin_amdgcn_s_barrier();
  }

  #pragma unroll
  for (int fm = 0; fm < 4; fm++) {
    #pragma unroll
    for (int fn = 0; fn < 6; fn++) {
      #pragma unroll
      for (int r2 = 0; r2 < 4; r2++) {
        int row = bm*128 + wr*64 + fm*16 + lg*4 + r2;
        int col = bn*192 + wc*96 + fn*16 + lr;
        Cb[(size_t)row * N + col] = (bf16_t)acc[fm][fn][r2];
      }
    }
  }
}

// ---------------- GEMM2: 128x256, 8 waves x (64x64), 1-barrier/K-step, f32 out ----------------
__global__ __launch_bounds__(512, 2) void gemm2_kernel(
    const bf16_t* __restrict__ A, const bf16_t* __restrict__ Bt,
    float* __restrict__ Cf, int M, int N, int K, int NBM) {
  __shared__ bf16_t As[2 * 128 * 64];   // 32 KB
  __shared__ bf16_t Bs[2 * 256 * 64];   // 64 KB
  int tid = threadIdx.x;
  int w = tid >> 6, l = tid & 63, lr = l & 15, lg = l >> 4;
  int wr = w >> 2, wc = w & 3;          // 2M x 4N waves; wave = 64 x 64
  int nwg = gridDim.x;
  int wg  = blockIdx.x;
  int cpx = nwg >> 3;
  int swz = (wg & 7) * cpx + (wg >> 3);
  int bm = swz % NBM, bn = swz / NBM;
  const int NT = K >> 6;

  auto stageA = [&](int tt) {
    bf16_t* ldsb = As + (tt & 1)*8192;
    #pragma unroll
    for (int i = 0; i < 2; i++) {
      int c = tid + i*512;
      int row = c >> 3;
      int scn = (c & 7) ^ (row & 7);
      gld_lds16(A + ((size_t)bm*128 + row) * K + tt*64 + scn*8,
                ldsb + i*4096 + w*512);
    }
  };
  auto stageB = [&](int tt, int u) {
    bf16_t* ldsb = Bs + (tt & 1)*16384 + u*8192;
    #pragma unroll
    for (int i = 0; i < 2; i++) {
      int c = tid + i*512;
      int row = c >> 3;
      int scn = (c & 7) ^ (row & 7);
      gld_lds16(Bt + ((size_t)bn*256 + u*128 + row) * K + tt*64 + scn*8,
                ldsb + i*4096 + w*512);
    }
  };
  auto afrag = [&](int b2, int row, int kk) -> bf16x8 {
    int chunk = (kk*4 + lg) ^ (row & 7);
    return *(const bf16x8*)((const char*)(As + b2*8192) + row*128 + chunk*16);
  };
  auto bfrag = [&](int b2, int row, int kk) -> bf16x8 {
    int chunk = (kk*4 + lg) ^ (row & 7);
    return *(const bf16x8*)((const char*)(Bs + b2*16384) + row*128 + chunk*16);
  };

  f32x4 acc[4][4] = {};
  bf16x8 a[4][2], bb[4][2];

  stageA(0); stageB(0, 0); stageB(0, 1);
  asm volatile("s_waitcnt vmcnt(0)" ::: "memory");
  __builtin_amdgcn_s_barrier();

  for (int t = 0; t < NT; t++) {
    int b = t & 1;
    #pragma unroll
    for (int fm = 0; fm < 4; fm++)
      #pragma unroll
      for (int kk = 0; kk < 2; kk++)
        a[fm][kk] = afrag(b, wr*64 + fm*16 + lr, kk);
    #pragma unroll
    for (int fn = 0; fn < 4; fn++)
      #pragma unroll
      for (int kk = 0; kk < 2; kk++)
        bb[fn][kk] = bfrag(b, wc*64 + fn*16 + lr, kk);
    if (t + 1 < NT) { stageA(t + 1); stageB(t + 1, 0); stageB(t + 1, 1); }
    asm volatile("s_waitcnt lgkmcnt(0)" ::: "memory");
    __builtin_amdgcn_s_setprio(1);
    #pragma unroll
    for (int fm = 0; fm < 4; fm++)
      #pragma unroll
      for (int fn = 0; fn < 4; fn++)
        #pragma unroll
        for (int kk = 0; kk < 2; kk++)
          acc[fm][fn] = __builtin_amdgcn_mfma_f32_16x16x32_bf16(a[fm][kk], bb[fn][kk], acc[fm][fn], 0, 0, 0);
    __builtin_amdgcn_s_setprio(0);
    asm volatile("s_waitcnt vmcnt(0)" ::: "memory");
    __builtin_amdgcn_s_barrier();
  }

  #pragma unroll
  for (int fm = 0; fm < 4; fm++) {
    #pragma unroll
    for (int fn = 0; fn < 4; fn++) {
      #pragma unroll
      for (int r2 = 0; r2 < 4; r2++) {
        int row = bm*128 + wr*64 + fm*16 + lg*4 + r2;
        int col = bn*256 + wc*64 + fn*16 + lr;
        Cf[(size_t)row * N + col] = acc[fm][fn][r2];
      }
    }
  }
}

// ---------------- fused RMSNorm + RoPE + q-scale ----------------
__global__ __launch_bounds__(256) void normrope_kernel(bf16_t* __restrict__ qkv,
    const float* __restrict__ qw, const float* __restrict__ kw,
    const float* __restrict__ sc) {
  int t = blockIdx.x;
  int tid = threadIdx.x;
  bf16_t* qrow = qkv + (size_t)t * QKVD;
  bf16_t* krow = qrow + QD;
  __shared__ float red[8];
  float s = 0.f;
  {
    const bf16x8* p = (const bf16x8*)(qrow + tid*16);
    bf16x8 v0 = p[0], v1 = p[1];
    #pragma unroll
    for (int j = 0; j < 8; j++) { float a = (float)v0[j], b = (float)v1[j]; s += a*a + b*b; }
  }
  #pragma unroll
  for (int o = 32; o; o >>= 1) s += __shfl_xor(s, o);
  if ((tid & 63) == 0) red[tid >> 6] = s;
  float sk = 0.f;
  {
    bf16x4 v = *(const bf16x4*)(krow + tid*4);
    #pragma unroll
    for (int j = 0; j < 4; j++) { float a = (float)v[j]; sk += a*a; }
  }
  #pragma unroll
  for (int o = 32; o; o >>= 1) sk += __shfl_xor(sk, o);
  if ((tid & 63) == 0) red[4 + (tid >> 6)] = sk;
  __syncthreads();
  float rq = rsqrtf((red[0]+red[1]+red[2]+red[3]) / (float)QD + 1e-6f);
  float rk = rsqrtf((red[4]+red[5]+red[6]+red[7]) / (float)KD + 1e-6f);
  const float ascale = 0.08838834764831845f;
  for (int p = tid; p < 2048; p += 256) {
    int hh = p >> 6, i = p & 63;
    int i1 = hh*HD + i, i2 = i1 + 64;
    float x1 = (float)qrow[i1] * rq * qw[i1];
    float x2 = (float)qrow[i2] * rq * qw[i2];
    float sn = sc[(t*64 + i)*2 + 0], cs = sc[(t*64 + i)*2 + 1];
    qrow[i1] = (bf16_t)((x1*cs - x2*sn) * ascale);
    qrow[i2] = (bf16_t)((x2*cs + x1*sn) * ascale);
  }
  for (int p = tid; p < 512; p += 256) {
    int hh = p >> 6, i = p & 63;
    int i1 = hh*HD + i, i2 = i1 + 64;
    float x1 = (float)krow[i1] * rk * kw[i1];
    float x2 = (float)krow[i2] * rk * kw[i2];
    float sn = sc[(t*64 + i)*2 + 0], cs = sc[(t*64 + i)*2 + 1];
    krow[i1] = (bf16_t)(x1*cs - x2*sn);
    krow[i2] = (bf16_t)(x2*cs + x1*sn);
  }
}

// ---------------- flash attention: 4 waves x 32 q-rows (R19-proven, unchanged) ----------------
__global__ __launch_bounds__(256, 2) void attn_kernel(const bf16_t* __restrict__ qkv,
    const int* __restrict__ positions, const int* __restrict__ seg,
    bf16_t* __restrict__ O) {
  __shared__ bf16_t Ks[2][64 * HD];   // 32 KB double-buffered
  __shared__ bf16_t Vt[HD * VS];      // 18 KB
  __shared__ bf16_t P[4][32 * VS];    // 18.4 KB
  __shared__ int posL[WMAX];
  __shared__ int segL[WMAX];
  int tid = threadIdx.x;
  int w = tid >> 6, l = tid & 63, lr = l & 15, lg = l >> 4;
  int qb = (gridDim.x - 1 - blockIdx.x) * 128;   // long blocks first
  int h = blockIdx.y;
  int kvh = h >> 2;
  int q0 = qb + w * 32;
  const bf16_t* Kg = qkv + QD + (size_t)kvh * HD;
  const bf16_t* Vg = qkv + QD + KD + (size_t)kvh * HD;

  bf16x8 qf[2][4];
  #pragma unroll
  for (int g = 0; g < 2; g++) {
    const bf16_t* Qrow = qkv + (size_t)(q0 + g*16 + lr) * QKVD + h * HD;
    #pragma unroll
    for (int c = 0; c < 4; c++) qf[g][c] = *(const bf16x8*)(Qrow + c*32 + lg*8);
  }
  int pos_i[2][4], seg_i[2][4];
  #pragma unroll
  for (int g = 0; g < 2; g++)
    #pragma unroll
    for (int r = 0; r < 4; r++) {
      int i = q0 + g*16 + lg*4 + r;
      pos_i[g][r] = positions[i]; seg_i[g][r] = seg[i];
    }
  f32x4 o[2][8] = {};
  float m[2][4], lsum[2][4];
  #pragma unroll
  for (int g = 0; g < 2; g++)
    #pragma unroll
    for (int r = 0; r < 4; r++) { m[g][r] = -__builtin_inff(); lsum[g][r] = 0.f; }

  int vkp[2], vdg[2];
  #pragma unroll
  for (int si = 0; si < 2; si++) { int item = tid + si*256; vkp[si] = item & 31; vdg[si] = item >> 5; }
  bf16x8 vrA[2], vrB[2];

  auto issueK = [&](int j0, int buf) {
    #pragma unroll
    for (int i = 0; i < 4; i++) {
      int c = tid + i*256;
      int row = c >> 4;
      int scn = (c & 15) ^ (row & 7);
      gld_lds16(Kg + (size_t)(j0 + row) * QKVD + scn*8,
                (char*)Ks[buf] + (size_t)(i*256 + (tid & 192))*16);
    }
  };
  auto loadV = [&](int j0) {
    #pragma unroll
    for (int si = 0; si < 2; si++) {
      const bf16_t* vp = Vg + (size_t)(j0 + 2*vkp[si]) * QKVD + vdg[si]*8;
      vrA[si] = *(const bf16x8*)vp;
      vrB[si] = *(const bf16x8*)(vp + QKVD);
    }
  };

  int jstart = qb - (WIN - 1); if (jstart < 0) jstart = 0; jstart &= ~63;
  const int jlast = qb + 64;
  const int wlen = qb + 128 - jstart;
  loadV(jstart);
  issueK(jstart, 0);
  for (int i = tid; i < wlen; i += 256) {
    posL[i] = positions[jstart + i];
    segL[i] = seg[jstart + i];
  }
  asm volatile("s_waitcnt lgkmcnt(0)" ::: "memory");
  __builtin_amdgcn_s_barrier();

  int nt = 0;
  for (int j0 = jstart; j0 <= jlast; j0 += 64, nt++) {
    int b = nt & 1;
    bool hasNext = (j0 + 64 <= jlast);
    #pragma unroll
    for (int si = 0; si < 2; si++) {
      #pragma unroll
      for (int e = 0; e < 8; e++) {
        bf16x2 pr; pr[0] = vrA[si][e]; pr[1] = vrB[si][e];
        *(bf16x2*)(Vt + (vdg[si]*8 + e)*VS + 2*vkp[si]) = pr;
      }
    }
    int pj[4], sj[4];
    #pragma unroll
    for (int kt = 0; kt < 4; kt++) {
      int ji = j0 - jstart + kt*16 + lr;
      pj[kt] = posL[ji]; sj[kt] = segL[ji];
    }
    asm volatile("" ::: "memory");
    if (hasNext) { loadV(j0 + 64); issueK(j0 + 64, b ^ 1); }
    asm volatile("" ::: "memory");
    if (hasNext) asm volatile("s_waitcnt vmcnt(8) lgkmcnt(0)" ::: "memory");
    else         asm volatile("s_waitcnt vmcnt(0) lgkmcnt(0)" ::: "memory");
    __builtin_amdgcn_s_barrier();

    bool active = (j0 <= q0 + 31) && (j0 + 63 >= q0 - (WIN - 1));
    if (active) {
      f32x4 s[2][4] = {};
      __builtin_amdgcn_s_setprio(1);
      #pragma unroll
      for (int kt = 0; kt < 4; kt++) {
        int row = kt*16 + lr;
        const char* kb = (const char*)Ks[b] + row*256;
        #pragma unroll
        for (int c = 0; c < 4; c++) {
          bf16x8 kf = *(const bf16x8*)(kb + (((c*4 + lg) ^ (row & 7)) * 16));
          #pragma unroll
          for (int g = 0; g < 2; g++)
            s[g][kt] = __builtin_amdgcn_mfma_f32_16x16x32_bf16(qf[g][c], kf, s[g][kt], 0, 0, 0);
        }
      }
      __builtin_amdgcn_s_setprio(0);
      #pragma unroll
      for (int kt = 0; kt < 4; kt++)
        #pragma unroll
        for (int g = 0; g < 2; g++)
          #pragma unroll
          for (int r = 0; r < 4; r++) {
            bool valid = (pj[kt] <= pos_i[g][r]) && (pos_i[g][r] - pj[kt] < WIN) && (seg_i[g][r] == sj[kt]) && (sj[kt] != 0);
            s[g][kt][r] = valid ? s[g][kt][r] : -__builtin_inff();
          }
      #pragma unroll
      for (int g = 0; g < 2; g++)
        #pragma unroll
        for (int r = 0; r < 4; r++) {
          float smax = fmaxf(fmaxf(s[g][0][r], s[g][1][r]), fmaxf(s[g][2][r], s[g][3][r]));
          if (__any(smax > m[g][r] + 8.f)) {
            float rm = smax;
            #pragma unroll
            for (int o2 = 1; o2 < 16; o2 <<= 1) rm = fmaxf(rm, __shfl_xor(rm, o2));
            if (rm > m[g][r] + 8.f) {
              float rescale = __expf(m[g][r] - rm);
              lsum[g][r] *= rescale;
              #pragma unroll
              for (int n = 0; n < 8; n++) o[g][n][r] *= rescale;
              m[g][r] = rm;
            }
          }
          float mub = fmaxf(m[g][r], -1e37f);
          float p0 = __expf(s[g][0][r] - mub);
          float p1 = __expf(s[g][1][r] - mub);
          float p2 = __expf(s[g][2][r] - mub);
          float p3 = __expf(s[g][3][r] - mub);
          lsum[g][r] += (p0 + p1) + (p2 + p3);
          int prow = (g*16 + lg*4 + r) * VS;
          P[w][prow + lr]      = (bf16_t)p0;
          P[w][prow + 16 + lr] = (bf16_t)p1;
          P[w][prow + 32 + lr] = (bf16_t)p2;
          P[w][prow + 48 + lr] = (bf16_t)p3;
        }
      __builtin_amdgcn_s_setprio(1);
      #pragma unroll
      for (int ks = 0; ks < 2; ks++) {
        bf16x8 pa[2];
        #pragma unroll
        for (int g = 0; g < 2; g++)
          pa[g] = *(const bf16x8*)(&P[w][(g*16 + lr)*VS + ks*32 + lg*8]);
        #pragma unroll
        for (int n = 0; n < 8; n++) {
          bf16x8 vb = *(const bf16x8*)(&Vt[(n*16 + lr)*VS + ks*32 + lg*8]);
          #pragma unroll
          for (int g = 0; g < 2; g++)
            o[g][n] = __builtin_amdgcn_mfma_f32_16x16x32_bf16(pa[g], vb, o[g][n], 0, 0, 0);
        }
      }
      __builtin_amdgcn_s_setprio(0);
    }
    __builtin_amdgcn_s_barrier();
  }
  #pragma unroll
  for (int g = 0; g < 2; g++)
    #pragma unroll
    for (int r = 0; r < 4; r++) {
      float ls = lsum[g][r];
      #pragma unroll
      for (int o2 = 1; o2 < 16; o2 <<= 1) ls += __shfl_xor(ls, o2);
      float inv = ls > 0.f ? 1.f / ls : 0.f;
      int row = q0 + g*16 + lg*4 + r;
      #pragma unroll
      for (int n = 0; n < 8; n++)
        O[(size_t)row * QD + h*HD + n*16 + lr] = (bf16_t)(o[g][n][r] * inv);
    }
}

// ---------------- launch ----------------
extern "C" void kernel_launch(void* const* d_in, const int* in_sizes, int n_in,
                              void* d_out, int out_size, void* d_ws, size_t ws_size,
                              hipStream_t stream) {
  (void)in_sizes; (void)n_in; (void)out_size; (void)ws_size;
  const float* x  = (const float*)d_in[0];
  const float* Wq = (const float*)d_in[1];
  const float* Wk = (const float*)d_in[2];
  const float* Wv = (const float*)d_in[3];
  const float* Wo = (const float*)d_in[4];
  const float* qw = (const float*)d_in[5];
  const float* kw = (const float*)d_in[6];
  const int*  seg = (const int*)d_in[7];
  float* out = (float*)d_out;

  char* base = (char*)d_ws;
  size_t off = 0;
  auto alloc = [&](size_t b) { void* r = base + off; off = (off + b + 255) & ~(size_t)255; return r; };
  bf16_t* xb    = (bf16_t*)alloc((size_t)T_LEN * DMODEL * 2);
  bf16_t* Wallt = (bf16_t*)alloc((size_t)QKVD * DMODEL * 2);
  bf16_t* Wot   = (bf16_t*)alloc((size_t)DMODEL * QD * 2);
  bf16_t* qkv   = (bf16_t*)alloc((size_t)T_LEN * QKVD * 2);
  int*    posi  = (int*)alloc((size_t)T_LEN * 4);
  float*  sc    = (float*)alloc((size_t)T_LEN * 64 * 2 * 4);
  bf16_t* ao    = xb;  // attention output aliases xb (xb dead after GEMM1)

  pos_kernel<<<1, 256, 0, stream>>>(seg, posi);
  sincos_kernel<<<T_LEN, 64, 0, stream>>>(posi, sc);
  cvt_kernel<<<(T_LEN * DMODEL / 8 + 255) / 256, 256, 0, stream>>>(x, xb, T_LEN * DMODEL);
  transcvt_kernel<<<dim3(QD/32, DMODEL/32), dim3(32, 8), 0, stream>>>(Wq, Wallt, DMODEL, QD);
  transcvt_kernel<<<dim3(KD/32, DMODEL/32), dim3(32, 8), 0, stream>>>(Wk, Wallt + (size_t)QD * DMODEL, DMODEL, KD);
  transcvt_kernel<<<dim3(KD/32, DMODEL/32), dim3(32, 8), 0, stream>>>(Wv, Wallt + (size_t)(QD + KD) * DMODEL, DMODEL, KD);
  transcvt_kernel<<<dim3(DMODEL/32, QD/32), dim3(32, 8), 0, stream>>>(Wo, Wot, QD, DMODEL);
  gemm1_kernel<<<dim3((T_LEN/128)*(QKVD/192)), 256, 0, stream>>>(
      xb, Wallt, qkv, T_LEN, QKVD, DMODEL, T_LEN/128);
  normrope_kernel<<<T_LEN, 256, 0, stream>>>(qkv, qw, kw, sc);
  attn_kernel<<<dim3(T_LEN/128, NHEADS), 256, 0, stream>>>(qkv, posi, seg, ao);
  gemm2_kernel<<<dim3((T_LEN/128)*(DMODEL/256)), 512, 0, stream>>>(
      ao, Wot, out, T_LEN, DMODEL, QD, T_LEN/128);
}

// Round 28
// 310.558 us; speedup vs baseline: 1.0510x; 1.0117x over previous
//
#include <hip/hip_runtime.h>
#include <cstdint>
#include <cstddef>

typedef __bf16 bf16_t;
typedef __bf16 bf16x8 __attribute__((ext_vector_type(8)));
typedef __bf16 bf16x4 __attribute__((ext_vector_type(4)));
typedef __bf16 bf16x2 __attribute__((ext_vector_type(2)));
typedef float f32x4 __attribute__((ext_vector_type(4)));

#define T_LEN 2048
#define DMODEL 4096
#define NHEADS 32
#define KVHEADS 8
#define HD 128
#define QD 4096   // NHEADS*HD
#define KD 1024   // KVHEADS*HD
#define QKVD 6144 // QD + 2*KD
#define WIN 1024
#define VS 72     // padded stride for attn Vt/P tiles (144B = 9*16B)
#define WMAX 1152 // max mask-window entries per attn block

// ---------------- positions (argmax of segment row, first occurrence) ----------------
__global__ void pos_kernel(const int* __restrict__ seg, int* __restrict__ positions) {
  __shared__ int svals[256], sidx[256];
  int tid = threadIdx.x;
  int bestv = -2147483647 - 1, besti = 0;
  for (int t = tid; t < T_LEN; t += 256) {
    int v = seg[t];
    if (v > bestv) { bestv = v; besti = t; }
  }
  svals[tid] = bestv; sidx[tid] = besti;
  __syncthreads();
  for (int st = 128; st > 0; st >>= 1) {
    if (tid < st) {
      if (svals[tid+st] > svals[tid] || (svals[tid+st] == svals[tid] && sidx[tid+st] < sidx[tid])) {
        svals[tid] = svals[tid+st]; sidx[tid] = sidx[tid+st];
      }
    }
    __syncthreads();
  }
  int amax = sidx[0];
  for (int t = tid; t < T_LEN; t += 256)
    positions[t] = (seg[t] != 0) ? (t - amax) : (1 << 30);
}

// ---------------- rope sin/cos table ----------------
__global__ void sincos_kernel(const int* __restrict__ positions, float* __restrict__ sc) {
  int t = blockIdx.x, i = threadIdx.x; // 64 threads
  float inv = expf(-(float)i * (logf(500000.0f) / 64.0f));
  float ang = (float)positions[t] * inv;
  sc[(t*64 + i)*2 + 0] = sinf(ang);
  sc[(t*64 + i)*2 + 1] = cosf(ang);
}

// ---------------- f32 -> bf16 convert (8/thread) ----------------
__global__ void cvt_kernel(const float* __restrict__ in, bf16_t* __restrict__ out, int n) {
  int i = (blockIdx.x * blockDim.x + threadIdx.x) * 8;
  if (i >= n) return;
  float4 a = *(const float4*)(in + i);
  float4 b = *(const float4*)(in + i + 4);
  bf16x8 o;
  o[0]=(bf16_t)a.x; o[1]=(bf16_t)a.y; o[2]=(bf16_t)a.z; o[3]=(bf16_t)a.w;
  o[4]=(bf16_t)b.x; o[5]=(bf16_t)b.y; o[6]=(bf16_t)b.z; o[7]=(bf16_t)b.w;
  *(bf16x8*)(out + i) = o;
}

// ---------------- transpose + convert: W[K][N] f32 -> Wt[N][K] bf16 ----------------
// 64x64 tiles, 256 threads. float4 loads (16B/lane, coalesced), bf16x8 writes
// (16B/lane, 128B per n-row). LDS tile stride 65 f32: transposed read has 8
// rows/slot -> banks {0,8,16,24} = 2-way aliasing (free, m136).
__global__ __launch_bounds__(256) void transcvt_kernel(const float* __restrict__ W,
                                                        bf16_t* __restrict__ Wt, int K, int N) {
  __shared__ float tile[64][65];
  int tid = threadIdx.x;
  int bx = blockIdx.x;  // N/64
  int by = blockIdx.y;  // K/64
  #pragma unroll
  for (int it = 0; it < 4; it++) {
    int i = tid + it*256;
    int r = i >> 4;          // 0..63
    int c4 = i & 15;         // 0..15
    float4 v = *(const float4*)(W + (size_t)(by*64 + r) * N + bx*64 + c4*4);
    tile[r][c4*4+0] = v.x; tile[r][c4*4+1] = v.y;
    tile[r][c4*4+2] = v.z; tile[r][c4*4+3] = v.w;
  }
  __syncthreads();
  #pragma unroll
  for (int it = 0; it < 2; it++) {
    int i = tid + it*256;
    int n = i >> 3;          // 0..63
    int k8 = i & 7;          // 0..7
    bf16x8 o;
    #pragma unroll
    for (int e = 0; e < 8; e++) o[e] = (bf16_t)tile[k8*8 + e][n];
    *(bf16x8*)(Wt + (size_t)(bx*64 + n) * K + by*64 + k8*8) = o;
  }
}

__device__ __forceinline__ void gld_lds16(const void* g, void* l) {
  __builtin_amdgcn_global_load_lds((__attribute__((address_space(1))) void*)g,
                                   (__attribute__((address_space(3))) void*)l, 16, 0, 0);
}

// ---------------- GEMM1: 128x192, 4 waves x (64x96), 1-barrier/K-step (R24-proven) ----------------
__global__ __launch_bounds__(256, 2) void gemm1_kernel(
    const bf16_t* __restrict__ A, const bf16_t* __restrict__ Bt,
    bf16_t* __restrict__ Cb, int M, int N, int K, int NBM) {
  __shared__ bf16_t As[2 * 128 * 64];   // 32 KB
  __shared__ bf16_t Bs[2 * 192 * 64];   // 48 KB
  int tid = threadIdx.x;
  int w = tid >> 6, l = tid & 63, lr = l & 15, lg = l >> 4;
  int wr = w >> 1, wc = w & 1;          // 2M x 2N waves; wave = 64 x 96
  int nwg = gridDim.x;
  int wg  = blockIdx.x;
  int cpx = nwg >> 3;
  int swz = (wg & 7) * cpx + (wg >> 3);
  int bm = swz % NBM, bn = swz / NBM;
  const int NT = K >> 6;

  auto stageA = [&](int tt, int h) {
    bf16_t* ldsb = As + (tt & 1)*8192 + h*4096;
    #pragma unroll
    for (int i = 0; i < 2; i++) {
      int c = tid + i*256;
      int row = c >> 3;
      int scn = (c & 7) ^ (row & 7);
      gld_lds16(A + ((size_t)bm*128 + h*64 + row) * K + tt*64 + scn*8,
                ldsb + i*2048 + w*512);
    }
  };
  auto stageB = [&](int tt, int u) {
    bf16_t* ldsb = Bs + (tt & 1)*12288 + u*4096;
    #pragma unroll
    for (int i = 0; i < 2; i++) {
      int c = tid + i*256;
      int row = c >> 3;
      int scn = (c & 7) ^ (row & 7);
      gld_lds16(Bt + ((size_t)bn*192 + u*64 + row) * K + tt*64 + scn*8,
                ldsb + i*2048 + w*512);
    }
  };
  auto afrag = [&](int b2, int row, int kk) -> bf16x8 {
    int chunk = (kk*4 + lg) ^ (row & 7);
    return *(const bf16x8*)((const char*)(As + b2*8192) + row*128 + chunk*16);
  };
  auto bfrag = [&](int b2, int row, int kk) -> bf16x8 {
    int chunk = (kk*4 + lg) ^ (row & 7);
    return *(const bf16x8*)((const char*)(Bs + b2*12288) + row*128 + chunk*16);
  };

  f32x4 acc[4][6] = {};
  bf16x8 a[4][2], bb[6][2];

  stageA(0, 0); stageA(0, 1); stageB(0, 0); stageB(0, 1); stageB(0, 2);
  asm volatile("s_waitcnt vmcnt(0)" ::: "memory");
  __builtin_amdgcn_s_barrier();

  for (int t = 0; t < NT; t++) {
    int b = t & 1;
    #pragma unroll
    for (int fm = 0; fm < 4; fm++)
      #pragma unroll
      for (int kk = 0; kk < 2; kk++)
        a[fm][kk] = afrag(b, wr*64 + fm*16 + lr, kk);
    #pragma unroll
    for (int fn = 0; fn < 6; fn++)
      #pragma unroll
      for (int kk = 0; kk < 2; kk++)
        bb[fn][kk] = bfrag(b, wc*96 + fn*16 + lr, kk);
    if (t + 1 < NT) {
      stageA(t + 1, 0); stageA(t + 1, 1);
      stageB(t + 1, 0); stageB(t + 1, 1); stageB(t + 1, 2);
    }
    asm volatile("s_waitcnt lgkmcnt(0)" ::: "memory");
    __builtin_amdgcn_s_setprio(1);
    #pragma unroll
    for (int fm = 0; fm < 4; fm++)
      #pragma unroll
      for (int fn = 0; fn < 6; fn++)
        #pragma unroll
        for (int kk = 0; kk < 2; kk++)
          acc[fm][fn] = __builtin_amdgcn_mfma_f32_16x16x32_bf16(a[fm][kk], bb[fn][kk], acc[fm][fn], 0, 0, 0);
    __builtin_amdgcn_s_setprio(0);
    asm volatile("s_waitcnt vmcnt(0)" ::: "memory");
    __builtin_amdgcn_s_barrier();
  }

  #pragma unroll
  for (int fm = 0; fm < 4; fm++) {
    #pragma unroll
    for (int fn = 0; fn < 6; fn++) {
      #pragma unroll
      for (int r2 = 0; r2 < 4; r2++) {
        int row = bm*128 + wr*64 + fm*16 + lg*4 + r2;
        int col = bn*192 + wc*96 + fn*16 + lr;
        Cb[(size_t)row * N + col] = (bf16_t)acc[fm][fn][r2];
      }
    }
  }
}

// ---------------- GEMM2: 128x256, 8 waves x (64x64), 1-barrier/K-step, f32 out ----------------
__global__ __launch_bounds__(512, 2) void gemm2_kernel(
    const bf16_t* __restrict__ A, const bf16_t* __restrict__ Bt,
    float* __restrict__ Cf, int M, int N, int K, int NBM) {
  __shared__ bf16_t As[2 * 128 * 64];   // 32 KB
  __shared__ bf16_t Bs[2 * 256 * 64];   // 64 KB
  int tid = threadIdx.x;
  int w = tid >> 6, l = tid & 63, lr = l & 15, lg = l >> 4;
  int wr = w >> 2, wc = w & 3;          // 2M x 4N waves; wave = 64 x 64
  int nwg = gridDim.x;
  int wg  = blockIdx.x;
  int cpx = nwg >> 3;
  int swz = (wg & 7) * cpx + (wg >> 3);
  int bm = swz % NBM, bn = swz / NBM;
  const int NT = K >> 6;

  auto stageA = [&](int tt) {
    bf16_t* ldsb = As + (tt & 1)*8192;
    #pragma unroll
    for (int i = 0; i < 2; i++) {
      int c = tid + i*512;
      int row = c >> 3;
      int scn = (c & 7) ^ (row & 7);
      gld_lds16(A + ((size_t)bm*128 + row) * K + tt*64 + scn*8,
                ldsb + i*4096 + w*512);
    }
  };
  auto stageB = [&](int tt, int u) {
    bf16_t* ldsb = Bs + (tt & 1)*16384 + u*8192;
    #pragma unroll
    for (int i = 0; i < 2; i++) {
      int c = tid + i*512;
      int row = c >> 3;
      int scn = (c & 7) ^ (row & 7);
      gld_lds16(Bt + ((size_t)bn*256 + u*128 + row) * K + tt*64 + scn*8,
                ldsb + i*4096 + w*512);
    }
  };
  auto afrag = [&](int b2, int row, int kk) -> bf16x8 {
    int chunk = (kk*4 + lg) ^ (row & 7);
    return *(const bf16x8*)((const char*)(As + b2*8192) + row*128 + chunk*16);
  };
  auto bfrag = [&](int b2, int row, int kk) -> bf16x8 {
    int chunk = (kk*4 + lg) ^ (row & 7);
    return *(const bf16x8*)((const char*)(Bs + b2*16384) + row*128 + chunk*16);
  };

  f32x4 acc[4][4] = {};
  bf16x8 a[4][2], bb[4][2];

  stageA(0); stageB(0, 0); stageB(0, 1);
  asm volatile("s_waitcnt vmcnt(0)" ::: "memory");
  __builtin_amdgcn_s_barrier();

  for (int t = 0; t < NT; t++) {
    int b = t & 1;
    #pragma unroll
    for (int fm = 0; fm < 4; fm++)
      #pragma unroll
      for (int kk = 0; kk < 2; kk++)
        a[fm][kk] = afrag(b, wr*64 + fm*16 + lr, kk);
    #pragma unroll
    for (int fn = 0; fn < 4; fn++)
      #pragma unroll
      for (int kk = 0; kk < 2; kk++)
        bb[fn][kk] = bfrag(b, wc*64 + fn*16 + lr, kk);
    if (t + 1 < NT) { stageA(t + 1); stageB(t + 1, 0); stageB(t + 1, 1); }
    asm volatile("s_waitcnt lgkmcnt(0)" ::: "memory");
    __builtin_amdgcn_s_setprio(1);
    #pragma unroll
    for (int fm = 0; fm < 4; fm++)
      #pragma unroll
      for (int fn = 0; fn < 4; fn++)
        #pragma unroll
        for (int kk = 0; kk < 2; kk++)
          acc[fm][fn] = __builtin_amdgcn_mfma_f32_16x16x32_bf16(a[fm][kk], bb[fn][kk], acc[fm][fn], 0, 0, 0);
    __builtin_amdgcn_s_setprio(0);
    asm volatile("s_waitcnt vmcnt(0)" ::: "memory");
    __builtin_amdgcn_s_barrier();
  }

  #pragma unroll
  for (int fm = 0; fm < 4; fm++) {
    #pragma unroll
    for (int fn = 0; fn < 4; fn++) {
      #pragma unroll
      for (int r2 = 0; r2 < 4; r2++) {
        int row = bm*128 + wr*64 + fm*16 + lg*4 + r2;
        int col = bn*256 + wc*64 + fn*16 + lr;
        Cf[(size_t)row * N + col] = acc[fm][fn][r2];
      }
    }
  }
}

// ---------------- fused RMSNorm + RoPE + q-scale ----------------
__global__ __launch_bounds__(256) void normrope_kernel(bf16_t* __restrict__ qkv,
    const float* __restrict__ qw, const float* __restrict__ kw,
    const float* __restrict__ sc) {
  int t = blockIdx.x;
  int tid = threadIdx.x;
  bf16_t* qrow = qkv + (size_t)t * QKVD;
  bf16_t* krow = qrow + QD;
  __shared__ float red[8];
  float s = 0.f;
  {
    const bf16x8* p = (const bf16x8*)(qrow + tid*16);
    bf16x8 v0 = p[0], v1 = p[1];
    #pragma unroll
    for (int j = 0; j < 8; j++) { float a = (float)v0[j], b = (float)v1[j]; s += a*a + b*b; }
  }
  #pragma unroll
  for (int o = 32; o; o >>= 1) s += __shfl_xor(s, o);
  if ((tid & 63) == 0) red[tid >> 6] = s;
  float sk = 0.f;
  {
    bf16x4 v = *(const bf16x4*)(krow + tid*4);
    #pragma unroll
    for (int j = 0; j < 4; j++) { float a = (float)v[j]; sk += a*a; }
  }
  #pragma unroll
  for (int o = 32; o; o >>= 1) sk += __shfl_xor(sk, o);
  if ((tid & 63) == 0) red[4 + (tid >> 6)] = sk;
  __syncthreads();
  float rq = rsqrtf((red[0]+red[1]+red[2]+red[3]) / (float)QD + 1e-6f);
  float rk = rsqrtf((red[4]+red[5]+red[6]+red[7]) / (float)KD + 1e-6f);
  const float ascale = 0.08838834764831845f;
  for (int p = tid; p < 2048; p += 256) {
    int hh = p >> 6, i = p & 63;
    int i1 = hh*HD + i, i2 = i1 + 64;
    float x1 = (float)qrow[i1] * rq * qw[i1];
    float x2 = (float)qrow[i2] * rq * qw[i2];
    float sn = sc[(t*64 + i)*2 + 0], cs = sc[(t*64 + i)*2 + 1];
    qrow[i1] = (bf16_t)((x1*cs - x2*sn) * ascale);
    qrow[i2] = (bf16_t)((x2*cs + x1*sn) * ascale);
  }
  for (int p = tid; p < 512; p += 256) {
    int hh = p >> 6, i = p & 63;
    int i1 = hh*HD + i, i2 = i1 + 64;
    float x1 = (float)krow[i1] * rk * kw[i1];
    float x2 = (float)krow[i2] * rk * kw[i2];
    float sn = sc[(t*64 + i)*2 + 0], cs = sc[(t*64 + i)*2 + 1];
    krow[i1] = (bf16_t)(x1*cs - x2*sn);
    krow[i2] = (bf16_t)(x2*cs + x1*sn);
  }
}

// ---------------- flash attention: 4 waves x 32 q-rows (R19-proven, unchanged) ----------------
__global__ __launch_bounds__(256, 2) void attn_kernel(const bf16_t* __restrict__ qkv,
    const int* __restrict__ positions, const int* __restrict__ seg,
    bf16_t* __restrict__ O) {
  __shared__ bf16_t Ks[2][64 * HD];   // 32 KB double-buffered
  __shared__ bf16_t Vt[HD * VS];      // 18 KB
  __shared__ bf16_t P[4][32 * VS];    // 18.4 KB
  __shared__ int posL[WMAX];
  __shared__ int segL[WMAX];
  int tid = threadIdx.x;
  int w = tid >> 6, l = tid & 63, lr = l & 15, lg = l >> 4;
  int qb = (gridDim.x - 1 - blockIdx.x) * 128;   // long blocks first
  int h = blockIdx.y;
  int kvh = h >> 2;
  int q0 = qb + w * 32;
  const bf16_t* Kg = qkv + QD + (size_t)kvh * HD;
  const bf16_t* Vg = qkv + QD + KD + (size_t)kvh * HD;

  bf16x8 qf[2][4];
  #pragma unroll
  for (int g = 0; g < 2; g++) {
    const bf16_t* Qrow = qkv + (size_t)(q0 + g*16 + lr) * QKVD + h * HD;
    #pragma unroll
    for (int c = 0; c < 4; c++) qf[g][c] = *(const bf16x8*)(Qrow + c*32 + lg*8);
  }
  int pos_i[2][4], seg_i[2][4];
  #pragma unroll
  for (int g = 0; g < 2; g++)
    #pragma unroll
    for (int r = 0; r < 4; r++) {
      int i = q0 + g*16 + lg*4 + r;
      pos_i[g][r] = positions[i]; seg_i[g][r] = seg[i];
    }
  f32x4 o[2][8] = {};
  float m[2][4], lsum[2][4];
  #pragma unroll
  for (int g = 0; g < 2; g++)
    #pragma unroll
    for (int r = 0; r < 4; r++) { m[g][r] = -__builtin_inff(); lsum[g][r] = 0.f; }

  int vkp[2], vdg[2];
  #pragma unroll
  for (int si = 0; si < 2; si++) { int item = tid + si*256; vkp[si] = item & 31; vdg[si] = item >> 5; }
  bf16x8 vrA[2], vrB[2];

  auto issueK = [&](int j0, int buf) {
    #pragma unroll
    for (int i = 0; i < 4; i++) {
      int c = tid + i*256;
      int row = c >> 4;
      int scn = (c & 15) ^ (row & 7);
      gld_lds16(Kg + (size_t)(j0 + row) * QKVD + scn*8,
                (char*)Ks[buf] + (size_t)(i*256 + (tid & 192))*16);
    }
  };
  auto loadV = [&](int j0) {
    #pragma unroll
    for (int si = 0; si < 2; si++) {
      const bf16_t* vp = Vg + (size_t)(j0 + 2*vkp[si]) * QKVD + vdg[si]*8;
      vrA[si] = *(const bf16x8*)vp;
      vrB[si] = *(const bf16x8*)(vp + QKVD);
    }
  };

  int jstart = qb - (WIN - 1); if (jstart < 0) jstart = 0; jstart &= ~63;
  const int jlast = qb + 64;
  const int wlen = qb + 128 - jstart;
  loadV(jstart);
  issueK(jstart, 0);
  for (int i = tid; i < wlen; i += 256) {
    posL[i] = positions[jstart + i];
    segL[i] = seg[jstart + i];
  }
  asm volatile("s_waitcnt lgkmcnt(0)" ::: "memory");
  __builtin_amdgcn_s_barrier();

  int nt = 0;
  for (int j0 = jstart; j0 <= jlast; j0 += 64, nt++) {
    int b = nt & 1;
    bool hasNext = (j0 + 64 <= jlast);
    #pragma unroll
    for (int si = 0; si < 2; si++) {
      #pragma unroll
      for (int e = 0; e < 8; e++) {
        bf16x2 pr; pr[0] = vrA[si][e]; pr[1] = vrB[si][e];
        *(bf16x2*)(Vt + (vdg[si]*8 + e)*VS + 2*vkp[si]) = pr;
      }
    }
    int pj[4], sj[4];
    #pragma unroll
    for (int kt = 0; kt < 4; kt++) {
      int ji = j0 - jstart + kt*16 + lr;
      pj[kt] = posL[ji]; sj[kt] = segL[ji];
    }
    asm volatile("" ::: "memory");
    if (hasNext) { loadV(j0 + 64); issueK(j0 + 64, b ^ 1); }
    asm volatile("" ::: "memory");
    if (hasNext) asm volatile("s_waitcnt vmcnt(8) lgkmcnt(0)" ::: "memory");
    else         asm volatile("s_waitcnt vmcnt(0) lgkmcnt(0)" ::: "memory");
    __builtin_amdgcn_s_barrier();

    bool active = (j0 <= q0 + 31) && (j0 + 63 >= q0 - (WIN - 1));
    if (active) {
      f32x4 s[2][4] = {};
      __builtin_amdgcn_s_setprio(1);
      #pragma unroll
      for (int kt = 0; kt < 4; kt++) {
        int row = kt*16 + lr;
        const char* kb = (const char*)Ks[b] + row*256;
        #pragma unroll
        for (int c = 0; c < 4; c++) {
          bf16x8 kf = *(const bf16x8*)(kb + (((c*4 + lg) ^ (row & 7)) * 16));
          #pragma unroll
          for (int g = 0; g < 2; g++)
            s[g][kt] = __builtin_amdgcn_mfma_f32_16x16x32_bf16(qf[g][c], kf, s[g][kt], 0, 0, 0);
        }
      }
      __builtin_amdgcn_s_setprio(0);
      #pragma unroll
      for (int kt = 0; kt < 4; kt++)
        #pragma unroll
        for (int g = 0; g < 2; g++)
          #pragma unroll
          for (int r = 0; r < 4; r++) {
            bool valid = (pj[kt] <= pos_i[g][r]) && (pos_i[g][r] - pj[kt] < WIN) && (seg_i[g][r] == sj[kt]) && (sj[kt] != 0);
            s[g][kt][r] = valid ? s[g][kt][r] : -__builtin_inff();
          }
      #pragma unroll
      for (int g = 0; g < 2; g++)
        #pragma unroll
        for (int r = 0; r < 4; r++) {
          float smax = fmaxf(fmaxf(s[g][0][r], s[g][1][r]), fmaxf(s[g][2][r], s[g][3][r]));
          if (__any(smax > m[g][r] + 8.f)) {
            float rm = smax;
            #pragma unroll
            for (int o2 = 1; o2 < 16; o2 <<= 1) rm = fmaxf(rm, __shfl_xor(rm, o2));
            if (rm > m[g][r] + 8.f) {
              float rescale = __expf(m[g][r] - rm);
              lsum[g][r] *= rescale;
              #pragma unroll
              for (int n = 0; n < 8; n++) o[g][n][r] *= rescale;
              m[g][r] = rm;
            }
          }
          float mub = fmaxf(m[g][r], -1e37f);
          float p0 = __expf(s[g][0][r] - mub);
          float p1 = __expf(s[g][1][r] - mub);
          float p2 = __expf(s[g][2][r] - mub);
          float p3 = __expf(s[g][3][r] - mub);
          lsum[g][r] += (p0 + p1) + (p2 + p3);
          int prow = (g*16 + lg*4 + r) * VS;
          P[w][prow + lr]      = (bf16_t)p0;
          P[w][prow + 16 + lr] = (bf16_t)p1;
          P[w][prow + 32 + lr] = (bf16_t)p2;
          P[w][prow + 48 + lr] = (bf16_t)p3;
        }
      __builtin_amdgcn_s_setprio(1);
      #pragma unroll
      for (int ks = 0; ks < 2; ks++) {
        bf16x8 pa[2];
        #pragma unroll
        for (int g = 0; g < 2; g++)
          pa[g] = *(const bf16x8*)(&P[w][(g*16 + lr)*VS + ks*32 + lg*8]);
        #pragma unroll
        for (int n = 0; n < 8; n++) {
          bf16x8 vb = *(const bf16x8*)(&Vt[(n*16 + lr)*VS + ks*32 + lg*8]);
          #pragma unroll
          for (int g = 0; g < 2; g++)
            o[g][n] = __builtin_amdgcn_mfma_f32_16x16x32_bf16(pa[g], vb, o[g][n], 0, 0, 0);
        }
      }
      __builtin_amdgcn_s_setprio(0);
    }
    __builtin_amdgcn_s_barrier();
  }
  #pragma unroll
  for (int g = 0; g < 2; g++)
    #pragma unroll
    for (int r = 0; r < 4; r++) {
      float ls = lsum[g][r];
      #pragma unroll
      for (int o2 = 1; o2 < 16; o2 <<= 1) ls += __shfl_xor(ls, o2);
      float inv = ls > 0.f ? 1.f / ls : 0.f;
      int row = q0 + g*16 + lg*4 + r;
      #pragma unroll
      for (int n = 0; n < 8; n++)
        O[(size_t)row * QD + h*HD + n*16 + lr] = (bf16_t)(o[g][n][r] * inv);
    }
}

// ---------------- launch ----------------
extern "C" void kernel_launch(void* const* d_in, const int* in_sizes, int n_in,
                              void* d_out, int out_size, void* d_ws, size_t ws_size,
                              hipStream_t stream) {
  (void)in_sizes; (void)n_in; (void)out_size; (void)ws_size;
  const float* x  = (const float*)d_in[0];
  const float* Wq = (const float*)d_in[1];
  const float* Wk = (const float*)d_in[2];
  const float* Wv = (const float*)d_in[3];
  const float* Wo = (const float*)d_in[4];
  const float* qw = (const float*)d_in[5];
  const float* kw = (const float*)d_in[6];
  const int*  seg = (const int*)d_in[7];
  float* out = (float*)d_out;

  char* base = (char*)d_ws;
  size_t off = 0;
  auto alloc = [&](size_t b) { void* r = base + off; off = (off + b + 255) & ~(size_t)255; return r; };
  bf16_t* xb    = (bf16_t*)alloc((size_t)T_LEN * DMODEL * 2);
  bf16_t* Wallt = (bf16_t*)alloc((size_t)QKVD * DMODEL * 2);
  bf16_t* Wot   = (bf16_t*)alloc((size_t)DMODEL * QD * 2);
  bf16_t* qkv   = (bf16_t*)alloc((size_t)T_LEN * QKVD * 2);
  int*    posi  = (int*)alloc((size_t)T_LEN * 4);
  float*  sc    = (float*)alloc((size_t)T_LEN * 64 * 2 * 4);
  bf16_t* ao    = xb;  // attention output aliases xb (xb dead after GEMM1)

  pos_kernel<<<1, 256, 0, stream>>>(seg, posi);
  sincos_kernel<<<T_LEN, 64, 0, stream>>>(posi, sc);
  cvt_kernel<<<(T_LEN * DMODEL / 8 + 255) / 256, 256, 0, stream>>>(x, xb, T_LEN * DMODEL);
  transcvt_kernel<<<dim3(QD/64, DMODEL/64), 256, 0, stream>>>(Wq, Wallt, DMODEL, QD);
  transcvt_kernel<<<dim3(KD/64, DMODEL/64), 256, 0, stream>>>(Wk, Wallt + (size_t)QD * DMODEL, DMODEL, KD);
  transcvt_kernel<<<dim3(KD/64, DMODEL/64), 256, 0, stream>>>(Wv, Wallt + (size_t)(QD + KD) * DMODEL, DMODEL, KD);
  transcvt_kernel<<<dim3(DMODEL/64, QD/64), 256, 0, stream>>>(Wo, Wot, QD, DMODEL);
  gemm1_kernel<<<dim3((T_LEN/128)*(QKVD/192)), 256, 0, stream>>>(
      xb, Wallt, qkv, T_LEN, QKVD, DMODEL, T_LEN/128);
  normrope_kernel<<<T_LEN, 256, 0, stream>>>(qkv, qw, kw, sc);
  attn_kernel<<<dim3(T_LEN/128, NHEADS), 256, 0, stream>>>(qkv, posi, seg, ao);
  gemm2_kernel<<<dim3((T_LEN/128)*(DMODEL/256)), 512, 0, stream>>>(
      ao, Wot, out, T_LEN, DMODEL, QD, T_LEN/128);
}